// Round 9
// baseline (32.181 us; speedup 1.0000x reference)
//
#include <hip/hip_runtime.h>
#include <math.h>

// Problem constants (verified against setup_inputs): E=1024, CTX=1024.
#define EDIM 1024
#define CTXDIM 1024
#define H2 2048
#define NCOPY 16
#define CSTRIDE 576           // floats; 2304 B — distinct line-index per copy
#define SBASE 4112            // Sbuf copies base (floats)

// ws float layout:
//   [0    : 1024)  h first half  = C * relu(emb[x] @ Mw^T + Mb)
//   [1024 : 2048)  h second half = sum_c relu(emb[ctx] @ Mw^T + Mb)
//   [4096]         (unsigned) k_tail arrival counter (zeroed by k_h blk 0)
//   [4112 : 4112+16*576)  16 Sbuf copies; slot 0=logdet, 1=S_x,
//                         2..2+C)=pos, 2+C..2+C+CN)=neg  (slot = 1 + task)

#define ALD(p) __hip_atomic_load((p), __ATOMIC_RELAXED, __HIP_MEMORY_SCOPE_AGENT)

// ---------------- Kernel 1: h[2048] ----------------
// 256 blocks x 1024 thr (16 waves). Block owns 4 cols; wave (c,g) = col 4b+c,
// rows r ≡ g (mod 4) of the 1+C input rows (row 0 = x). Block 0 also zeroes
// the counter + Sbuf copies (stream order guarantees visibility in k_tail).
__global__ __launch_bounds__(1024) void k_h(
    const float* __restrict__ emb, const float* __restrict__ Mw,
    const float* __restrict__ Mb, const int* __restrict__ x,
    const int* __restrict__ ctx, int C, float* __restrict__ ws)
{
    __shared__ int   idxs[64];
    __shared__ float pacc[16];
    __shared__ float pxs[4];
    const int tid  = threadIdx.x;
    const int w    = tid >> 6;
    const int lane = tid & 63;
    const int c    = w & 3;
    const int g    = w >> 2;
    const int j    = blockIdx.x * 4 + c;

    if (blockIdx.x == 0) {
        for (int i = tid; i < NCOPY * CSTRIDE + 16; i += 1024)
            ws[4096 + i] = 0.f;
    }
    if (tid <= C) idxs[tid] = (tid == 0) ? x[0] : ctx[tid - 1];

    const float4* mrow = (const float4*)(Mw + (size_t)j * EDIM);
    const float4 mw0 = mrow[lane];
    const float4 mw1 = mrow[lane + 64];
    const float4 mw2 = mrow[lane + 128];
    const float4 mw3 = mrow[lane + 192];
    const float bj = Mb[j];
    __syncthreads();

    float acc = 0.f, px = 0.f;
#pragma unroll 2
    for (int r = g; r <= C; r += 4) {
        const int idx = idxs[r];
        const float4* e4 = (const float4*)(emb + (size_t)idx * EDIM);
        const float4 a  = e4[lane];
        const float4 bb = e4[lane + 64];
        const float4 d  = e4[lane + 128];
        const float4 e  = e4[lane + 192];
        float s = a.x*mw0.x + a.y*mw0.y + a.z*mw0.z + a.w*mw0.w;
        s += bb.x*mw1.x + bb.y*mw1.y + bb.z*mw1.z + bb.w*mw1.w;
        s += d.x*mw2.x + d.y*mw2.y + d.z*mw2.z + d.w*mw2.w;
        s += e.x*mw3.x + e.y*mw3.y + e.z*mw3.z + e.w*mw3.w;
#pragma unroll
        for (int m = 32; m >= 1; m >>= 1) s += __shfl_xor(s, m);
        const float v = fmaxf(s + bj, 0.f);
        if (r == 0) px = (float)C * v;   // x-row appears only in group 0
        else        acc += v;
    }
    if (lane == 0) {
        pacc[w] = acc;
        if (g == 0) pxs[c] = px;
    }
    __syncthreads();
    if (tid < 4) {
        const int jj = blockIdx.x * 4 + tid;
        ws[jj]          = pxs[tid];
        ws[CTXDIM + jj] = pacc[tid] + pacc[tid + 4] + pacc[tid + 8] + pacc[tid + 12];
    }
}

// ---------------- Kernel 2: column-slice tail ----------------
// 256 blocks x 512 thr (8 waves). Block b owns cols 4b..4b+3:
//   waves 0..3: mu_col = dot(Uw[col], h) + Ub   (one wave per col)
//   waves 4..7: sig_col = softplus(dot(Ww[col], h) + Wb)
// Each thread owns TWO task slots: t0 = tid, t1 = tid + 512 (551 tasks total;
// the thread with t1 == nkl takes the logdet partial instead). Partials go
// into Sbuf copy b&15 via atomicAdd. Last-arriving block reduces the copies
// and computes hinge + output.
__global__ __launch_bounds__(512) void k_tail(
    const float* __restrict__ Uw, const float* __restrict__ Ub,
    const float* __restrict__ Ww, const float* __restrict__ Wb,
    const float* __restrict__ pmu, const float* __restrict__ psig,
    const int* __restrict__ x, const int* __restrict__ ctx,
    const int* __restrict__ negs, int C, int CN, int NEG, int KDIM,
    int nblk, float* __restrict__ ws, float* __restrict__ out)
{
    __shared__ float4 hbuf4[512];          // h (2048 f32)
    __shared__ float  msig[8];             // [0:4) mu, [4:8) sigma (block's cols)
    __shared__ float  SL[553];             // winner-only: reduced S values
    __shared__ int    winflag;
    const int tid  = threadIdx.x;
    const int w    = tid >> 6;
    const int lane = tid & 63;
    const int b    = blockIdx.x;
    unsigned* cnt  = (unsigned*)(ws + 4096);

    // Early gathers: tasks t0 = tid, t1 = tid + 512 (one float4 of pmu + one
    // of psig each, cols 4b..4b+3). Issued before the GEMV to hide latency.
    const int nkl = 1 + C + CN;            // 551
    const int t0 = tid, t1 = tid + 512;
    const bool has0 = (t0 < nkl);
    const bool has1 = (t1 < nkl);
    float4 gm0, gs0, gm1, gs1;
    if (has0) {
        const int idx = (t0 == 0) ? x[0]
                       : (t0 <= C ? ctx[t0 - 1] : negs[t0 - 1 - C]);
        gm0 = *(const float4*)(pmu  + (size_t)idx * CTXDIM + 4 * b);
        gs0 = *(const float4*)(psig + (size_t)idx * CTXDIM + 4 * b);
    }
    if (has1) {
        const int idx = (t1 <= C) ? ctx[t1 - 1] : negs[t1 - 1 - C];
        gm1 = *(const float4*)(pmu  + (size_t)idx * CTXDIM + 4 * b);
        gs1 = *(const float4*)(psig + (size_t)idx * CTXDIM + 4 * b);
    }

    hbuf4[tid] = ((const float4*)ws)[tid];
    __syncthreads();

    // GEMV: one wave per (mu|sigma) column.
    {
        const int col = 4 * b + (w & 3);
        const float4* W4 = (const float4*)(((w < 4) ? Uw : Ww) + (size_t)col * H2);
        float s = 0.f;
#pragma unroll
        for (int k = 0; k < 8; ++k) {
            const float4 wv = W4[lane + 64 * k];
            const float4 hv = hbuf4[lane + 64 * k];
            s += wv.x*hv.x + wv.y*hv.y + wv.z*hv.z + wv.w*hv.w;
        }
#pragma unroll
        for (int m = 32; m >= 1; m >>= 1) s += __shfl_xor(s, m);
        if (lane == 0) {
            if (w < 4) {
                msig[w & 3] = s + Ub[col];
            } else {
                const float v = s + Wb[col];
                msig[4 + (w & 3)] = fmaxf(v, 0.f) + log1pf(expf(-fabsf(v)));
            }
        }
    }
    __syncthreads();

    // Per-task 4-col partials -> spread atomicAdds.
    float* copy = ws + SBASE + (size_t)(b & (NCOPY - 1)) * CSTRIDE;
    const float mu0 = msig[0], mu1 = msig[1], mu2 = msig[2], mu3 = msig[3];
    const float sg0 = msig[4], sg1 = msig[5], sg2 = msig[6], sg3 = msig[7];
    if (has0) {
        float acc = 0.f;
        { const float s2 = gs0.x*gs0.x; const float d = gm0.x - mu0; acc += (sg0 + d*d)/s2 + logf(s2); }
        { const float s2 = gs0.y*gs0.y; const float d = gm0.y - mu1; acc += (sg1 + d*d)/s2 + logf(s2); }
        { const float s2 = gs0.z*gs0.z; const float d = gm0.z - mu2; acc += (sg2 + d*d)/s2 + logf(s2); }
        { const float s2 = gs0.w*gs0.w; const float d = gm0.w - mu3; acc += (sg3 + d*d)/s2 + logf(s2); }
        atomicAdd(&copy[1 + t0], acc);             // slot = 1 + task
    }
    if (has1) {
        float acc = 0.f;
        { const float s2 = gs1.x*gs1.x; const float d = gm1.x - mu0; acc += (sg0 + d*d)/s2 + logf(s2); }
        { const float s2 = gs1.y*gs1.y; const float d = gm1.y - mu1; acc += (sg1 + d*d)/s2 + logf(s2); }
        { const float s2 = gs1.z*gs1.z; const float d = gm1.z - mu2; acc += (sg2 + d*d)/s2 + logf(s2); }
        { const float s2 = gs1.w*gs1.w; const float d = gm1.w - mu3; acc += (sg3 + d*d)/s2 + logf(s2); }
        atomicAdd(&copy[1 + t1], acc);
    } else if (t1 == nkl) {                        // tid 39: logdet partial
        const float ld = logf(sg0) + logf(sg1) + logf(sg2) + logf(sg3);
        atomicAdd(&copy[0], ld);
    }

    __syncthreads();                // atomics drained (vmcnt 0) before arrival
    if (tid == 0) {
        const unsigned old = __hip_atomic_fetch_add(cnt, 1u,
                               __ATOMIC_RELEASE, __HIP_MEMORY_SCOPE_AGENT);
        winflag = (old == (unsigned)(nblk - 1));
    }
    __syncthreads();
    if (!winflag) return;

    // Winner block: reduce 16 copies, hinge, output.
    __builtin_amdgcn_fence(__ATOMIC_ACQUIRE, "agent");
    for (int t = tid; t < 2 + C + CN; t += 512) {
        float sfull = 0.f;
#pragma unroll
        for (int cc = 0; cc < NCOPY; ++cc)
            sfull += ALD(&ws[SBASE + cc * CSTRIDE + t]);
        SL[t] = sfull;
    }
    __syncthreads();
    if (w == 0) {
        float lik = 0.f;
        for (int i = lane; i < CN; i += 64) {
            const float sn = SL[2 + C + i];
            const float sp = SL[2 + i / NEG];
            lik += fmaxf(0.f, 0.5f * (sn - sp) + 1.0f);   // kl_neg - kl_pos + 1
        }
#pragma unroll
        for (int m = 32; m >= 1; m >>= 1) lik += __shfl_xor(lik, m);
        if (lane == 0)
            out[0] = lik - 0.5f * (SL[1] - (float)KDIM - SL[0]);  // - kl_prior
    }
}

extern "C" void kernel_launch(void* const* d_in, const int* in_sizes, int n_in,
                              void* d_out, int out_size, void* d_ws, size_t ws_size,
                              hipStream_t stream) {
    const int*   x    = (const int*)d_in[0];
    const int*   ctx  = (const int*)d_in[1];
    const int*   negs = (const int*)d_in[2];
    const float* emb  = (const float*)d_in[3];
    const float* Mw   = (const float*)d_in[4];
    const float* Mb   = (const float*)d_in[5];
    const float* Uw   = (const float*)d_in[6];
    const float* Ub   = (const float*)d_in[7];
    const float* Ww   = (const float*)d_in[8];
    const float* Wb   = (const float*)d_in[9];
    const float* pmu  = (const float*)d_in[10];
    const float* psig = (const float*)d_in[11];
    float* ws  = (float*)d_ws;
    float* out = (float*)d_out;

    const int C    = in_sizes[1];          // 50
    const int CN   = in_sizes[2];          // 500
    const int NEG  = CN / C;               // 10
    const int KDIM = in_sizes[5];          // CTX = 1024

    k_h<<<CTXDIM / 4, 1024, 0, stream>>>(emb, Mw, Mb, x, ctx, C, ws);
    k_tail<<<CTXDIM / 4, 512, 0, stream>>>(Uw, Ub, Ww, Wb, pmu, psig,
                                           x, ctx, negs, C, CN, NEG, KDIM,
                                           CTXDIM / 4, ws, out);
}

// Round 10
// 32.082 us; speedup vs baseline: 1.0031x; 1.0031x over previous
//
#include <hip/hip_runtime.h>
#include <math.h>

// Problem constants (verified against setup_inputs): E=1024, CTX=1024.
#define EDIM 1024
#define CTXDIM 1024
#define H2 2048
#define NBLK 256

// ws float layout:
//   [0    : 1024)  h first half  (written via 4B agent atomic stores)
//   [1024 : 2048)  h second half
//   [2048 : 3072)  mu
//   [3072 : 4096)  sigma
//   [4096 : 5184)  barrier state, 34 x 128B lines (memset to 0 each launch):
//                  line i<16: leaf[i]; line 16: root; lines 17..32: done[i];
//                  line 33: finale counter
//   [5248 : 5248+552)  Sbuf: [0]=logdet, [1]=S_x, [2..52)=pos, [52..552)=neg
//
// Protocol: ALL cross-block data via relaxed agent-scope atomics (IF-coherent,
// proven absmax=0.0 in round 6). NO fences anywhere. Barrier arrivals are
// RELAXED RMWs through a 16-way tree; __syncthreads before arrival drains each
// wave's vmcnt so the block's atomic stores are acked at the coherence point.

#define AST(p, v) __hip_atomic_store((p), (v), __ATOMIC_RELAXED, __HIP_MEMORY_SCOPE_AGENT)
#define ALD(p)    __hip_atomic_load((p), __ATOMIC_RELAXED, __HIP_MEMORY_SCOPE_AGENT)

__device__ __forceinline__ void tree_bar(unsigned* base, int b) {
    __syncthreads();                          // block's atomic stores acked
    if (threadIdx.x == 0) {
        unsigned* leaf = base + 32 * (b & 15);
        unsigned* root = base + 32 * 16;
        unsigned* done = base + 32 * (17 + (b & 15));
        const unsigned gen = ALD(done);       // pre-arrival generation read
        const unsigned old = __hip_atomic_fetch_add(leaf, 1u,
                               __ATOMIC_RELAXED, __HIP_MEMORY_SCOPE_AGENT);
        if ((old & 15u) == 15u) {             // 16th arrival at this leaf
            const unsigned old2 = __hip_atomic_fetch_add(root, 1u,
                                   __ATOMIC_RELAXED, __HIP_MEMORY_SCOPE_AGENT);
            if ((old2 & 15u) == 15u) {        // last leaf: broadcast
#pragma unroll
                for (int i = 0; i < 16; ++i)
                    __hip_atomic_fetch_add(base + 32 * (17 + i), 1u,
                                           __ATOMIC_RELAXED, __HIP_MEMORY_SCOPE_AGENT);
            }
        }
        while (ALD(done) == gen) __builtin_amdgcn_s_sleep(8);
    }
    __syncthreads();
    __builtin_amdgcn_sched_barrier(0);        // no load hoisting above the spin
}

__global__ __launch_bounds__(1024) void k_fused(
    const float* __restrict__ emb, const float* __restrict__ Mw,
    const float* __restrict__ Mb, const float* __restrict__ Uw,
    const float* __restrict__ Ub, const float* __restrict__ Ww,
    const float* __restrict__ Wb, const float* __restrict__ pmu,
    const float* __restrict__ psig, const int* __restrict__ x,
    const int* __restrict__ ctx, const int* __restrict__ negs,
    int C, int CN, int NEG, int KDIM,
    float* __restrict__ ws, float* __restrict__ out)
{
    __shared__ int    idxs[64];
    __shared__ float  pacc[16];
    __shared__ float  pxs[4];
    __shared__ float  shbuf[2048];            // phase B: h; phase C: mu|sigma
    __shared__ int    winflag;

    const int tid  = threadIdx.x;
    const int w    = tid >> 6;
    const int lane = tid & 63;
    const int b    = blockIdx.x;
    unsigned* bar  = (unsigned*)(ws + 4096);
    float* Sbuf    = ws + 5248;

    // ---------------- Phase A: h[2048] ----------------
    // Block owns 4 cols; wave (c,g) = col 4b+c, rows r ≡ g (mod 4) of 1+C rows.
    {
        if (tid <= C) idxs[tid] = (tid == 0) ? x[0] : ctx[tid - 1];
        const int c = w & 3;
        const int g = w >> 2;
        const int j = b * 4 + c;
        const float4* mrow = (const float4*)(Mw + (size_t)j * EDIM);
        const float4 mw0 = mrow[lane];
        const float4 mw1 = mrow[lane + 64];
        const float4 mw2 = mrow[lane + 128];
        const float4 mw3 = mrow[lane + 192];
        const float bj = Mb[j];
        __syncthreads();

        float acc = 0.f, px = 0.f;
#pragma unroll 2
        for (int r = g; r <= C; r += 4) {
            const int idx = idxs[r];
            const float4* e4 = (const float4*)(emb + (size_t)idx * EDIM);
            const float4 a  = e4[lane];
            const float4 bb = e4[lane + 64];
            const float4 d  = e4[lane + 128];
            const float4 e  = e4[lane + 192];
            float s = a.x*mw0.x + a.y*mw0.y + a.z*mw0.z + a.w*mw0.w;
            s += bb.x*mw1.x + bb.y*mw1.y + bb.z*mw1.z + bb.w*mw1.w;
            s += d.x*mw2.x + d.y*mw2.y + d.z*mw2.z + d.w*mw2.w;
            s += e.x*mw3.x + e.y*mw3.y + e.z*mw3.z + e.w*mw3.w;
#pragma unroll
            for (int m = 32; m >= 1; m >>= 1) s += __shfl_xor(s, m);
            const float v = fmaxf(s + bj, 0.f);
            if (r == 0) px = (float)C * v;    // x-row appears only in group 0
            else        acc += v;
        }
        if (lane == 0) {
            pacc[w] = acc;
            if (g == 0) pxs[c] = px;
        }
        __syncthreads();
        if (tid < 4) {
            const int jj = b * 4 + tid;
            AST(&ws[jj], pxs[tid]);
            AST(&ws[CTXDIM + jj],
                pacc[tid] + pacc[tid + 4] + pacc[tid + 8] + pacc[tid + 12]);
        }
    }

    tree_bar(bar, b);

    // ---------------- Phase B: mu, sigma ----------------
    // 8 rows/block (rows 8b..8b+7), 2 waves/row (half each of the 2048-dot).
    {
        {   // stage h via 8B coherent loads (2 floats/thread)
            const unsigned long long v =
                __hip_atomic_load((const unsigned long long*)(ws + 2 * tid),
                                  __ATOMIC_RELAXED, __HIP_MEMORY_SCOPE_AGENT);
            shbuf[2 * tid]     = __uint_as_float((unsigned)(v & 0xffffffffu));
            shbuf[2 * tid + 1] = __uint_as_float((unsigned)(v >> 32));
        }
        __syncthreads();

        const int row  = b * 8 + (w >> 1);    // 0..2047
        const int half = w & 1;
        const bool is_mu = (row < CTXDIM);
        const int rr = row & (CTXDIM - 1);
        const float4* W4 = (const float4*)((is_mu ? Uw : Ww) + (size_t)rr * H2)
                           + half * 256;
        const float4* h4 = (const float4*)shbuf + half * 256;
        float s = 0.f;
#pragma unroll
        for (int k = 0; k < 4; ++k) {
            const float4 wv = W4[lane + 64 * k];
            const float4 hv = h4[lane + 64 * k];
            s += wv.x*hv.x + wv.y*hv.y + wv.z*hv.z + wv.w*hv.w;
        }
#pragma unroll
        for (int m = 32; m >= 1; m >>= 1) s += __shfl_xor(s, m);
        if (lane == 0) pacc[w] = s;
        __syncthreads();
        if (half == 0 && lane == 0) {
            const float tot = pacc[w] + pacc[w + 1];
            if (is_mu) {
                AST(&ws[2048 + rr], tot + Ub[rr]);
            } else {
                const float v = tot + Wb[rr];
                AST(&ws[3072 + rr], fmaxf(v, 0.f) + log1pf(expf(-fabsf(v))));
            }
        }
    }

    tree_bar(bar, b);

    // ---------------- Phase C: per-task S + fused finale ----------------
    // Task t = b + 256*w for w<3. t0: logdet; t1: x; [2,2+C): pos; rest: neg.
    {
        {   // stage mu|sigma via 8B coherent loads
            const unsigned long long v =
                __hip_atomic_load((const unsigned long long*)(ws + 2048 + 2 * tid),
                                  __ATOMIC_RELAXED, __HIP_MEMORY_SCOPE_AGENT);
            shbuf[2 * tid]     = __uint_as_float((unsigned)(v & 0xffffffffu));
            shbuf[2 * tid + 1] = __uint_as_float((unsigned)(v >> 32));
        }
        __syncthreads();

        const int ntask = 2 + C + CN;         // 552
        const int t = b + NBLK * w;
        if (w < 3 && t < ntask) {
            float acc = 0.f;
            if (t == 0) {                     // logdet = sum log sigma
#pragma unroll
                for (int k = 0; k < 16; ++k) acc += logf(shbuf[1024 + lane + 64 * k]);
            } else {
                int idx;
                if (t == 1)          idx = idxs[0];
                else if (t < 2 + C)  idx = idxs[t - 1];
                else                 idx = negs[t - 2 - C];
                const float4* m4  = (const float4*)(pmu  + (size_t)idx * CTXDIM);
                const float4* s4  = (const float4*)(psig + (size_t)idx * CTXDIM);
                const float4* mu4 = (const float4*)shbuf;
                const float4* sg4 = (const float4*)shbuf + 256;
#pragma unroll
                for (int k = 0; k < 4; ++k) {
                    const int i = lane + 64 * k;
                    const float4 m  = m4[i];
                    const float4 sv = s4[i];
                    const float4 mu = mu4[i];
                    const float4 sg = sg4[i];
                    { const float s2 = sv.x*sv.x; const float dd = m.x-mu.x; acc += (sg.x + dd*dd)/s2 + logf(s2); }
                    { const float s2 = sv.y*sv.y; const float dd = m.y-mu.y; acc += (sg.y + dd*dd)/s2 + logf(s2); }
                    { const float s2 = sv.z*sv.z; const float dd = m.z-mu.z; acc += (sg.z + dd*dd)/s2 + logf(s2); }
                    { const float s2 = sv.w*sv.w; const float dd = m.w-mu.w; acc += (sg.w + dd*dd)/s2 + logf(s2); }
                }
            }
#pragma unroll
            for (int m = 32; m >= 1; m >>= 1) acc += __shfl_xor(acc, m);
            if (lane == 0) AST(&Sbuf[t], acc);
        }

        __syncthreads();                      // block's Sbuf stores acked
        if (tid == 0) {
            const unsigned old = __hip_atomic_fetch_add(bar + 32 * 33, 1u,
                                   __ATOMIC_RELAXED, __HIP_MEMORY_SCOPE_AGENT);
            winflag = (old == (unsigned)(NBLK - 1));
        }
        __syncthreads();
        __builtin_amdgcn_sched_barrier(0);
        if (winflag && w == 0) {              // last-arriving block, wave 0
            float lik = 0.f;
            for (int i = lane; i < CN; i += 64) {
                const float sn = ALD(&Sbuf[2 + C + i]);
                const float sp = ALD(&Sbuf[2 + i / NEG]);
                lik += fmaxf(0.f, 0.5f * (sn - sp) + 1.0f);   // kl_neg - kl_pos + 1
            }
#pragma unroll
            for (int m = 32; m >= 1; m >>= 1) lik += __shfl_xor(lik, m);
            if (lane == 0) {
                const float ld = ALD(&Sbuf[0]);
                const float sx = ALD(&Sbuf[1]);
                out[0] = lik - 0.5f * (sx - (float)KDIM - ld);  // - kl_prior
            }
        }
    }
}

extern "C" void kernel_launch(void* const* d_in, const int* in_sizes, int n_in,
                              void* d_out, int out_size, void* d_ws, size_t ws_size,
                              hipStream_t stream) {
    const int*   x    = (const int*)d_in[0];
    const int*   ctx  = (const int*)d_in[1];
    const int*   negs = (const int*)d_in[2];
    const float* emb  = (const float*)d_in[3];
    const float* Mw   = (const float*)d_in[4];
    const float* Mb   = (const float*)d_in[5];
    const float* Uw   = (const float*)d_in[6];
    const float* Ub   = (const float*)d_in[7];
    const float* Ww   = (const float*)d_in[8];
    const float* Wb   = (const float*)d_in[9];
    const float* pmu  = (const float*)d_in[10];
    const float* psig = (const float*)d_in[11];
    float* ws  = (float*)d_ws;
    float* out = (float*)d_out;

    const int C    = in_sizes[1];          // 50
    const int CN   = in_sizes[2];          // 500
    const int NEG  = CN / C;               // 10
    const int KDIM = in_sizes[5];          // CTX = 1024

    // Zero the 34-line barrier state each launch (graph-legal async memset).
    (void)hipMemsetAsync((char*)d_ws + 4096 * sizeof(float), 0,
                         34 * 128, stream);
    k_fused<<<NBLK, 1024, 0, stream>>>(emb, Mw, Mb, Uw, Ub, Ww, Wb, pmu, psig,
                                       x, ctx, negs, C, CN, NEG, KDIM, ws, out);
}

// Round 11
// 26.767 us; speedup vs baseline: 1.2023x; 1.1986x over previous
//
#include <hip/hip_runtime.h>
#include <math.h>

// Problem constants (verified against setup_inputs): E=1024, CTX=1024.
#define EDIM 1024
#define CTXDIM 1024
#define H2 2048

// ws float layout:
//   [0    : 1024)  h first half  = C * relu(emb[x] @ Mw^T + Mb)
//   [1024 : 2048)  h second half = sum_c relu(emb[ctx] @ Mw^T + Mb)
//   [2048 : 3072)  mu
//   [3072 : 4096)  sigma
//   [4096 : 4099)  unsigned counters; cnt[2] = k_S arrival counter
//   [4100 : ...)   S: S[0]=logdet, S[1]=S_x, S[2..2+C)=pos, S[2+C..)=neg

// ---------------- Kernel 1: h[2048] ----------------
// 256 blocks x 1024 thr (16 waves). Block owns 4 cols; wave (c,g) = col 4b+c,
// rows r ≡ g (mod 4) of the 1+C input rows (row 0 = x). ctx indices preloaded
// into LDS so the row loop has no dependent global scalar loads.
__global__ __launch_bounds__(1024) void k_h(
    const float* __restrict__ emb, const float* __restrict__ Mw,
    const float* __restrict__ Mb, const int* __restrict__ x,
    const int* __restrict__ ctx, int C, float* __restrict__ ws)
{
    __shared__ int   idxs[64];
    __shared__ float pacc[16];
    __shared__ float pxs[4];
    const int tid  = threadIdx.x;
    const int w    = tid >> 6;
    const int lane = tid & 63;
    const int c    = w & 3;
    const int g    = w >> 2;
    const int j    = blockIdx.x * 4 + c;

    if (tid <= C) idxs[tid] = (tid == 0) ? x[0] : ctx[tid - 1];

    const float4* mrow = (const float4*)(Mw + (size_t)j * EDIM);
    const float4 mw0 = mrow[lane];
    const float4 mw1 = mrow[lane + 64];
    const float4 mw2 = mrow[lane + 128];
    const float4 mw3 = mrow[lane + 192];
    const float bj = Mb[j];
    __syncthreads();

    float acc = 0.f, px = 0.f;
#pragma unroll 2
    for (int r = g; r <= C; r += 4) {
        const int idx = idxs[r];
        const float4* e4 = (const float4*)(emb + (size_t)idx * EDIM);
        const float4 a  = e4[lane];
        const float4 bb = e4[lane + 64];
        const float4 d  = e4[lane + 128];
        const float4 e  = e4[lane + 192];
        float s = a.x*mw0.x + a.y*mw0.y + a.z*mw0.z + a.w*mw0.w;
        s += bb.x*mw1.x + bb.y*mw1.y + bb.z*mw1.z + bb.w*mw1.w;
        s += d.x*mw2.x + d.y*mw2.y + d.z*mw2.z + d.w*mw2.w;
        s += e.x*mw3.x + e.y*mw3.y + e.z*mw3.z + e.w*mw3.w;
#pragma unroll
        for (int m = 32; m >= 1; m >>= 1) s += __shfl_xor(s, m);
        const float v = fmaxf(s + bj, 0.f);
        if (r == 0) px = (float)C * v;   // x-row appears only in group 0
        else        acc += v;
    }
    if (lane == 0) {
        pacc[w] = acc;
        if (g == 0) pxs[c] = px;
    }
    __syncthreads();
    if (tid < 4) {
        const int jj = blockIdx.x * 4 + tid;
        ws[jj]          = pxs[tid];
        ws[CTXDIM + jj] = pacc[tid] + pacc[tid + 4] + pacc[tid + 8] + pacc[tid + 12];
    }
}

// ---------------- Kernel 2: mu, sigma ----------------
// 256 blocks x 1024 thr (16 waves). 8 rows/block, 2 waves/row (each wave does
// half of the 2048-dot; halves combined in LDS). 4 waves/SIMD for latency
// hiding on the (L2-resident) 16 MB weight stream.
__global__ __launch_bounds__(1024) void k_musig(
    const float* __restrict__ Uw, const float* __restrict__ Ub,
    const float* __restrict__ Ww, const float* __restrict__ Wb,
    float* __restrict__ ws)
{
    if (blockIdx.x == 0 && threadIdx.x == 0) {
        __hip_atomic_store((unsigned*)(ws + 4096) + 2, 0u,
                           __ATOMIC_RELAXED, __HIP_MEMORY_SCOPE_AGENT);
    }
    __shared__ float4 hbuf[512];                   // h (2048 f32)
    __shared__ float  part[16];
    const int tid = threadIdx.x;
    if (tid < 512) hbuf[tid] = ((const float4*)ws)[tid];
    __syncthreads();

    const int w = tid >> 6, lane = tid & 63;
    const int row  = blockIdx.x * 8 + (w >> 1);    // 0..2047
    const int half = w & 1;
    const bool is_mu = (row < CTXDIM);
    const int rr = row & (CTXDIM - 1);
    const float4* W4 = (const float4*)((is_mu ? Uw : Ww) + (size_t)rr * H2)
                       + half * 256;
    const float4* h4 = hbuf + half * 256;

    float s = 0.f;
#pragma unroll
    for (int k = 0; k < 4; ++k) {
        const float4 wv = W4[lane + 64 * k];
        const float4 hv = h4[lane + 64 * k];
        s += wv.x*hv.x + wv.y*hv.y + wv.z*hv.z + wv.w*hv.w;
    }
#pragma unroll
    for (int m = 32; m >= 1; m >>= 1) s += __shfl_xor(s, m);
    if (lane == 0) part[w] = s;
    __syncthreads();
    if (half == 0 && lane == 0) {
        const float tot = part[w] + part[w + 1];
        if (is_mu) {
            ws[2048 + rr] = tot + Ub[rr];
        } else {
            const float v = tot + Wb[rr];
            ws[3072 + rr] = fmaxf(v, 0.f) + log1pf(expf(-fabsf(v)));  // softplus
        }
    }
}

// ---------------- Kernel 3: per-candidate S + fused finale ----------------
// 4 tasks per 256-thr block. t0: logdet; t1: x; [2,2+C): pos; rest: neg.
// Prior gathers issued into registers BEFORE the LDS staging of mu/sigma so
// the idx-dependent load latency hides under the staging + barrier.
__global__ __launch_bounds__(256) void k_S(
    const float* __restrict__ pmu, const float* __restrict__ psig,
    const int* __restrict__ x, const int* __restrict__ ctx,
    const int* __restrict__ negs, int C, int CN, int NEG, int KDIM,
    int nblk, float* __restrict__ ws, float* __restrict__ out)
{
    __shared__ float musig[2048];                  // [0:1024) mu, [1024:2048) sigma
    const int tid = threadIdx.x;
    const int w = tid >> 6, lane = tid & 63;
    const int t = blockIdx.x * 4 + w;
    const int ntask = 2 + C + CN;
    float* Sbuf = ws + 4100;
    unsigned* cnt = (unsigned*)(ws + 4096) + 2;
    float4* ms4 = (float4*)musig;

    // 1) Issue idx load + prior gathers into registers (no LDS dependency).
    const bool iskl = (t >= 1 && t < ntask);
    float4 gm[4], gsv[4];
    if (iskl) {
        int idx;
        if (t == 1)          idx = x[0];
        else if (t < 2 + C)  idx = ctx[t - 2];
        else                 idx = negs[t - 2 - C];
        const float4* m4 = (const float4*)(pmu  + (size_t)idx * CTXDIM);
        const float4* s4 = (const float4*)(psig + (size_t)idx * CTXDIM);
#pragma unroll
        for (int k = 0; k < 4; ++k) {
            gm[k]  = m4[lane + 64 * k];
            gsv[k] = s4[lane + 64 * k];
        }
    }

    // 2) Stage mu/sigma under the gather latency.
    ms4[tid]       = ((const float4*)(ws + 2048))[tid];
    ms4[tid + 256] = ((const float4*)(ws + 2048))[tid + 256];
    __syncthreads();

    // 3) Compute.
    if (t < ntask) {
        float acc = 0.f;
        if (t == 0) {          // logdet = sum log sigma
#pragma unroll
            for (int k = 0; k < 16; ++k) acc += logf(musig[1024 + lane + 64 * k]);
        } else {
#pragma unroll
            for (int k = 0; k < 4; ++k) {
                const int i = lane + 64 * k;
                const float4 m  = gm[k];
                const float4 sv = gsv[k];
                const float4 mu = ms4[i];
                const float4 sg = ms4[256 + i];
                { const float s2 = sv.x*sv.x; const float dd = m.x-mu.x; acc += (sg.x + dd*dd)/s2 + logf(s2); }
                { const float s2 = sv.y*sv.y; const float dd = m.y-mu.y; acc += (sg.y + dd*dd)/s2 + logf(s2); }
                { const float s2 = sv.z*sv.z; const float dd = m.z-mu.z; acc += (sg.z + dd*dd)/s2 + logf(s2); }
                { const float s2 = sv.w*sv.w; const float dd = m.w-mu.w; acc += (sg.w + dd*dd)/s2 + logf(s2); }
            }
        }
#pragma unroll
        for (int m = 32; m >= 1; m >>= 1) acc += __shfl_xor(acc, m);
        if (lane == 0)
            __hip_atomic_store(&Sbuf[t], acc, __ATOMIC_RELAXED, __HIP_MEMORY_SCOPE_AGENT);
    }

    __syncthreads();                // all 4 waves' Sbuf stores drained
    if (w == 0) {                   // wave-uniform from here
        __builtin_amdgcn_fence(__ATOMIC_RELEASE, "agent");   // one wb per block
        int win = 0;
        if (lane == 0) {
            const unsigned old = __hip_atomic_fetch_add(cnt, 1u,
                                   __ATOMIC_RELAXED, __HIP_MEMORY_SCOPE_AGENT);
            win = (old == (unsigned)(nblk - 1));
        }
        win = __shfl(win, 0);
        if (win) {
            __builtin_amdgcn_fence(__ATOMIC_ACQUIRE, "agent");
            float lik = 0.f;
            for (int i = lane; i < CN; i += 64) {
                const float sn = __hip_atomic_load(&Sbuf[2 + C + i],
                                   __ATOMIC_RELAXED, __HIP_MEMORY_SCOPE_AGENT);
                const float sp = __hip_atomic_load(&Sbuf[2 + i / NEG],
                                   __ATOMIC_RELAXED, __HIP_MEMORY_SCOPE_AGENT);
                lik += fmaxf(0.f, 0.5f * (sn - sp) + 1.0f);   // kl_neg - kl_pos + 1
            }
#pragma unroll
            for (int m = 32; m >= 1; m >>= 1) lik += __shfl_xor(lik, m);
            if (lane == 0) {
                const float ld = __hip_atomic_load(&Sbuf[0],
                                   __ATOMIC_RELAXED, __HIP_MEMORY_SCOPE_AGENT);
                const float sx = __hip_atomic_load(&Sbuf[1],
                                   __ATOMIC_RELAXED, __HIP_MEMORY_SCOPE_AGENT);
                out[0] = lik - 0.5f * (sx - (float)KDIM - ld);  // - kl_prior
            }
        }
    }
}

extern "C" void kernel_launch(void* const* d_in, const int* in_sizes, int n_in,
                              void* d_out, int out_size, void* d_ws, size_t ws_size,
                              hipStream_t stream) {
    const int*   x    = (const int*)d_in[0];
    const int*   ctx  = (const int*)d_in[1];
    const int*   negs = (const int*)d_in[2];
    const float* emb  = (const float*)d_in[3];
    const float* Mw   = (const float*)d_in[4];
    const float* Mb   = (const float*)d_in[5];
    const float* Uw   = (const float*)d_in[6];
    const float* Ub   = (const float*)d_in[7];
    const float* Ww   = (const float*)d_in[8];
    const float* Wb   = (const float*)d_in[9];
    const float* pmu  = (const float*)d_in[10];
    const float* psig = (const float*)d_in[11];
    float* ws  = (float*)d_ws;
    float* out = (float*)d_out;

    const int C    = in_sizes[1];          // 50
    const int CN   = in_sizes[2];          // 500
    const int NEG  = CN / C;               // 10
    const int KDIM = in_sizes[5];          // CTX = 1024

    k_h<<<CTXDIM / 4, 1024, 0, stream>>>(emb, Mw, Mb, x, ctx, C, ws);
    k_musig<<<256, 1024, 0, stream>>>(Uw, Ub, Ww, Wb, ws);
    const int ntask = 2 + C + CN;
    const int nblk  = (ntask + 3) / 4;
    k_S<<<nblk, 256, 0, stream>>>(pmu, psig, x, ctx, negs,
                                  C, CN, NEG, KDIM, nblk, ws, out);
}

// Round 12
// 24.585 us; speedup vs baseline: 1.3090x; 1.0887x over previous
//
#include <hip/hip_runtime.h>
#include <math.h>

// Problem constants (verified against setup_inputs): E=1024, CTX=1024.
#define EDIM 1024
#define CTXDIM 1024
#define H2 2048

// ws float layout:
//   [0    : 2048)  h
//   [2048 : 3072)  mu      (K2: written via relaxed agent-atomic stores)
//   [3072 : 4096)  sigma
//   [4096 : 5184)  barrier state: 34 x 128B lines (zeroed by k_h block 0):
//                  line i<16: leaf[i]; line 16: root; 17..32: done[i]; 33: finale
//   [5248 : 5800)  Sbuf: [0]=logdet, [1]=S_x, [2..52)=pos, [52..552)=neg

#define AST(p, v) __hip_atomic_store((p), (v), __ATOMIC_RELAXED, __HIP_MEMORY_SCOPE_AGENT)
#define ALD(p)    __hip_atomic_load((p), __ATOMIC_RELAXED, __HIP_MEMORY_SCOPE_AGENT)

// ---------------- Kernel 1: h[2048] ----------------
// 256 blocks x 1024 thr (16 waves). Block owns 4 cols; wave (c,g) = col 4b+c,
// rows r ≡ g (mod 4) of the 1+C input rows (row 0 = x). Block 0 zeroes the
// K2 barrier state (stream order + kernel-boundary flush make it visible).
__global__ __launch_bounds__(1024) void k_h(
    const float* __restrict__ emb, const float* __restrict__ Mw,
    const float* __restrict__ Mb, const int* __restrict__ x,
    const int* __restrict__ ctx, int C, float* __restrict__ ws)
{
    __shared__ int   idxs[64];
    __shared__ float pacc[16];
    __shared__ float pxs[4];
    const int tid  = threadIdx.x;
    const int w    = tid >> 6;
    const int lane = tid & 63;
    const int c    = w & 3;
    const int g    = w >> 2;
    const int j    = blockIdx.x * 4 + c;

    if (blockIdx.x == 0) {
        ws[4096 + tid] = 0.f;                  // 1024 of the 1088 counter words
        if (tid < 64) ws[5120 + tid] = 0.f;    // remainder
    }
    if (tid <= C) idxs[tid] = (tid == 0) ? x[0] : ctx[tid - 1];

    const float4* mrow = (const float4*)(Mw + (size_t)j * EDIM);
    const float4 mw0 = mrow[lane];
    const float4 mw1 = mrow[lane + 64];
    const float4 mw2 = mrow[lane + 128];
    const float4 mw3 = mrow[lane + 192];
    const float bj = Mb[j];
    __syncthreads();

    float acc = 0.f, px = 0.f;
#pragma unroll 2
    for (int r = g; r <= C; r += 4) {
        const int idx = idxs[r];
        const float4* e4 = (const float4*)(emb + (size_t)idx * EDIM);
        const float4 a  = e4[lane];
        const float4 bb = e4[lane + 64];
        const float4 d  = e4[lane + 128];
        const float4 e  = e4[lane + 192];
        float s = a.x*mw0.x + a.y*mw0.y + a.z*mw0.z + a.w*mw0.w;
        s += bb.x*mw1.x + bb.y*mw1.y + bb.z*mw1.z + bb.w*mw1.w;
        s += d.x*mw2.x + d.y*mw2.y + d.z*mw2.z + d.w*mw2.w;
        s += e.x*mw3.x + e.y*mw3.y + e.z*mw3.z + e.w*mw3.w;
#pragma unroll
        for (int m = 32; m >= 1; m >>= 1) s += __shfl_xor(s, m);
        const float v = fmaxf(s + bj, 0.f);
        if (r == 0) px = (float)C * v;   // x-row appears only in group 0
        else        acc += v;
    }
    if (lane == 0) {
        pacc[w] = acc;
        if (g == 0) pxs[c] = px;
    }
    __syncthreads();
    if (tid < 4) {
        const int jj = blockIdx.x * 4 + tid;
        ws[jj]          = pxs[tid];
        ws[CTXDIM + jj] = pacc[tid] + pacc[tid + 4] + pacc[tid + 8] + pacc[tid + 12];
    }
}

// ---------------- Kernel 2: producer-consumer tail ----------------
// 325 blocks x 512 thr.
//   Blocks 0..255 (producers): round-5 k_musig body verbatim — 8 rows/block,
//     one wave per row, full 2048-dot; mu/sigma stored via relaxed agent
//     atomics; tree arrival (16 leaves -> root -> 16 done flags).
//   Blocks 256..324 (consumers): 8 S-tasks/block (t = (b-256)*8 + w; 552 total).
//     Prior gathers issued into registers BEFORE the spin (latency hidden).
//     Spin on sharded done flag, stage mu/sigma via 8B atomic loads, compute,
//     store S via atomic store; last-arriving consumer computes hinge + out.
__global__ __launch_bounds__(512) void k_tail(
    const float* __restrict__ Uw, const float* __restrict__ Ub,
    const float* __restrict__ Ww, const float* __restrict__ Wb,
    const float* __restrict__ pmu, const float* __restrict__ psig,
    const int* __restrict__ x, const int* __restrict__ ctx,
    const int* __restrict__ negs, int C, int CN, int NEG, int KDIM,
    int nsblk, float* __restrict__ ws, float* __restrict__ out)
{
    __shared__ float smem[2048];               // producers: h; consumers: mu|sigma
    __shared__ int   winflag;
    const int tid  = threadIdx.x;
    const int w    = tid >> 6;
    const int lane = tid & 63;
    const int b    = blockIdx.x;
    unsigned* bar  = (unsigned*)(ws + 4096);
    float* Sbuf    = ws + 5248;

    if (b < 256) {
        // ---------------- producer: mu, sigma ----------------
        float4* hbuf = (float4*)smem;
        hbuf[tid] = ((const float4*)ws)[tid];  // h from k_h (kernel boundary)
        __syncthreads();

        const int W = b * 8 + w;               // 0..2047
        const bool is_mu = (W < CTXDIM);
        const int rr = W & (CTXDIM - 1);
        const float4* Wr4 = (const float4*)((is_mu ? Uw : Ww) + (size_t)rr * H2);
        float s = 0.f;
#pragma unroll
        for (int k = 0; k < 8; ++k) {
            const float4 wv = Wr4[lane + 64 * k];
            const float4 hv = hbuf[lane + 64 * k];
            s += wv.x*hv.x + wv.y*hv.y + wv.z*hv.z + wv.w*hv.w;
        }
#pragma unroll
        for (int m = 32; m >= 1; m >>= 1) s += __shfl_xor(s, m);
        if (lane == 0) {
            if (is_mu) {
                AST(&ws[2048 + rr], s + Ub[rr]);
            } else {
                const float v = s + Wb[rr];
                AST(&ws[3072 + rr], fmaxf(v, 0.f) + log1pf(expf(-fabsf(v))));
            }
        }
        __syncthreads();                       // block's stores acked at CP
        if (tid == 0) {
            const unsigned old = __hip_atomic_fetch_add(&bar[32 * (b & 15)], 1u,
                                   __ATOMIC_RELAXED, __HIP_MEMORY_SCOPE_AGENT);
            if (old == 15u) {                  // leaf full
                const unsigned o2 = __hip_atomic_fetch_add(&bar[32 * 16], 1u,
                                      __ATOMIC_RELAXED, __HIP_MEMORY_SCOPE_AGENT);
                if (o2 == 15u) {               // all leaves: broadcast done
#pragma unroll
                    for (int i = 0; i < 16; ++i)
                        AST(&bar[32 * (17 + i)], 1u);
                }
            }
        }
        return;
    }

    // ---------------- consumer: S tasks + finale ----------------
    const int t = (b - 256) * 8 + w;           // 0..551
    const int ntask = 2 + C + CN;              // 552

    // 1) Issue prior gathers into registers before the spin.
    const bool iskl = (t >= 1 && t < ntask);
    float4 gm[4], gsv[4];
    if (iskl) {
        int idx;
        if (t == 1)          idx = x[0];
        else if (t < 2 + C)  idx = ctx[t - 2];
        else                 idx = negs[t - 2 - C];
        const float4* m4 = (const float4*)(pmu  + (size_t)idx * CTXDIM);
        const float4* s4 = (const float4*)(psig + (size_t)idx * CTXDIM);
#pragma unroll
        for (int k = 0; k < 4; ++k) {
            gm[k]  = m4[lane + 64 * k];
            gsv[k] = s4[lane + 64 * k];
        }
    }

    // 2) Spin until producers done (sharded flag; gathers complete meanwhile).
    if (tid == 0) {
        while (ALD(&bar[32 * (17 + (b & 15))]) == 0u)
            __builtin_amdgcn_s_sleep(8);
    }
    __syncthreads();
    __builtin_amdgcn_sched_barrier(0);         // no hoisting above the spin

    // 3) Stage mu/sigma via 8B coherent loads (2 per thread).
    {
        const unsigned long long* src = (const unsigned long long*)(ws + 2048);
#pragma unroll
        for (int q = 0; q < 2; ++q) {
            const int i = tid + 512 * q;
            const unsigned long long v = __hip_atomic_load(&src[i],
                __ATOMIC_RELAXED, __HIP_MEMORY_SCOPE_AGENT);
            smem[2 * i]     = __uint_as_float((unsigned)(v & 0xffffffffu));
            smem[2 * i + 1] = __uint_as_float((unsigned)(v >> 32));
        }
    }
    __syncthreads();

    // 4) Compute S(t).
    {
        float acc = 0.f;
        if (t == 0) {                          // logdet = sum log sigma
#pragma unroll
            for (int k = 0; k < 16; ++k) acc += logf(smem[1024 + lane + 64 * k]);
        } else {
            const float4* ms4 = (const float4*)smem;
#pragma unroll
            for (int k = 0; k < 4; ++k) {
                const int i = lane + 64 * k;
                const float4 m  = gm[k];
                const float4 sv = gsv[k];
                const float4 mu = ms4[i];
                const float4 sg = ms4[256 + i];
                { const float s2 = sv.x*sv.x; const float dd = m.x-mu.x; acc += (sg.x + dd*dd)/s2 + logf(s2); }
                { const float s2 = sv.y*sv.y; const float dd = m.y-mu.y; acc += (sg.y + dd*dd)/s2 + logf(s2); }
                { const float s2 = sv.z*sv.z; const float dd = m.z-mu.z; acc += (sg.z + dd*dd)/s2 + logf(s2); }
                { const float s2 = sv.w*sv.w; const float dd = m.w-mu.w; acc += (sg.w + dd*dd)/s2 + logf(s2); }
            }
        }
#pragma unroll
        for (int m = 32; m >= 1; m >>= 1) acc += __shfl_xor(acc, m);
        if (lane == 0) AST(&Sbuf[t], acc);
    }

    __syncthreads();                           // block's S stores drained
    if (w == 0) {                              // wave-uniform finale protocol
        __builtin_amdgcn_fence(__ATOMIC_RELEASE, "agent");   // one wb per block
        int win = 0;
        if (lane == 0) {
            const unsigned old = __hip_atomic_fetch_add(&bar[32 * 33], 1u,
                                   __ATOMIC_RELAXED, __HIP_MEMORY_SCOPE_AGENT);
            win = (old == (unsigned)(nsblk - 1));
        }
        win = __shfl(win, 0);
        if (win) {
            __builtin_amdgcn_fence(__ATOMIC_ACQUIRE, "agent");
            float lik = 0.f;
            for (int i = lane; i < CN; i += 64) {
                const float sn = ALD(&Sbuf[2 + C + i]);
                const float sp = ALD(&Sbuf[2 + i / NEG]);
                lik += fmaxf(0.f, 0.5f * (sn - sp) + 1.0f);   // kl_neg - kl_pos + 1
            }
#pragma unroll
            for (int m = 32; m >= 1; m >>= 1) lik += __shfl_xor(lik, m);
            if (lane == 0) {
                const float ld = ALD(&Sbuf[0]);
                const float sx = ALD(&Sbuf[1]);
                out[0] = lik - 0.5f * (sx - (float)KDIM - ld);  // - kl_prior
            }
        }
    }
}

extern "C" void kernel_launch(void* const* d_in, const int* in_sizes, int n_in,
                              void* d_out, int out_size, void* d_ws, size_t ws_size,
                              hipStream_t stream) {
    const int*   x    = (const int*)d_in[0];
    const int*   ctx  = (const int*)d_in[1];
    const int*   negs = (const int*)d_in[2];
    const float* emb  = (const float*)d_in[3];
    const float* Mw   = (const float*)d_in[4];
    const float* Mb   = (const float*)d_in[5];
    const float* Uw   = (const float*)d_in[6];
    const float* Ub   = (const float*)d_in[7];
    const float* Ww   = (const float*)d_in[8];
    const float* Wb   = (const float*)d_in[9];
    const float* pmu  = (const float*)d_in[10];
    const float* psig = (const float*)d_in[11];
    float* ws  = (float*)d_ws;
    float* out = (float*)d_out;

    const int C    = in_sizes[1];          // 50
    const int CN   = in_sizes[2];          // 500
    const int NEG  = CN / C;               // 10
    const int KDIM = in_sizes[5];          // CTX = 1024

    const int ntask = 2 + C + CN;          // 552
    const int nsblk = (ntask + 7) / 8;     // 69 consumer blocks

    k_h<<<CTXDIM / 4, 1024, 0, stream>>>(emb, Mw, Mb, x, ctx, C, ws);
    k_tail<<<256 + nsblk, 512, 0, stream>>>(Uw, Ub, Ww, Wb, pmu, psig,
                                            x, ctx, negs, C, CN, NEG, KDIM,
                                            nsblk, ws, out);
}